// Round 5
// baseline (1330.709 us; speedup 1.0000x reference)
//
#include <hip/hip_runtime.h>
#include <hip/hip_bf16.h>

// Problem: T=256, B=128, DIN=20, H=1024, OUT=1095, L=3
//   h = x @ W1 + b1                       (T*B,20)x(20,1024)
//   3x SRU: U = h @ W_sru[l]  (T*B,1024)x(1024,3072); gates z|f|r
//           scan over T: c = f*c + (1-f)*z ; h = r*c + (1-r)*h_in
//   out = h @ W3 + b3                     (T*B,1024)x(1024,1095)
// fp32 in/out; bf16 MFMA internally, fp32 accumulate, c carried fp32.

#define T_DIM 256
#define B_DIM 128
#define DIN 20
#define H_DIM 1024
#define OUT_DIM 1095
#define L_DIM 3
#define M_DIM (T_DIM * B_DIM)        // 32768
#define H3 (3 * H_DIM)               // 3072
#define OUT_ELEMS ((size_t)M_DIM * OUT_DIM)   // 35,880,960

typedef __bf16 bf16x8 __attribute__((ext_vector_type(8)));
typedef __bf16 bf16x4 __attribute__((ext_vector_type(4)));
typedef __bf16 bf16x2 __attribute__((ext_vector_type(2)));
typedef float f32x4 __attribute__((ext_vector_type(4)));

__device__ __forceinline__ void async16(const __bf16* g, __bf16* l) {
  __builtin_amdgcn_global_load_lds(
      (const __attribute__((address_space(1))) void*)g,
      (__attribute__((address_space(3))) void*)l, 16, 0, 0);
}

// raw barrier with compiler memory fences (does NOT drain vmcnt)
__device__ __forceinline__ void bar() {
  asm volatile("" ::: "memory");
  __builtin_amdgcn_s_barrier();
  asm volatile("" ::: "memory");
}

// ---- transpose + cast W_sru (L,H,3H) fp32 -> (L,3H,H) bf16 ----
__global__ void transpose_sru(const float* __restrict__ W, __bf16* __restrict__ Wt) {
  __shared__ float tile[32][33];
  int l = blockIdx.z;
  int j0 = blockIdx.x * 32;
  int i0 = blockIdx.y * 32;
  int tx = threadIdx.x, ty = threadIdx.y;  // 32x8
  const float* Wl = W + (size_t)l * H_DIM * H3;
  __bf16* Wtl = Wt + (size_t)l * H_DIM * H3;
#pragma unroll
  for (int r = 0; r < 4; r++)
    tile[ty + r * 8][tx] = Wl[(size_t)(i0 + ty + r * 8) * H3 + j0 + tx];
  __syncthreads();
#pragma unroll
  for (int r = 0; r < 4; r++)
    Wtl[(size_t)(j0 + ty + r * 8) * H_DIM + i0 + tx] = (__bf16)tile[tx][ty + r * 8];
}

// ---- transpose + cast W3 (H,OUT) fp32 -> (OUT,H) bf16 ----
__global__ void transpose_w3(const float* __restrict__ W, __bf16* __restrict__ Wt) {
  __shared__ float tile[32][33];
  int j0 = blockIdx.x * 32;
  int i0 = blockIdx.y * 32;
  int tx = threadIdx.x, ty = threadIdx.y;
#pragma unroll
  for (int r = 0; r < 4; r++) {
    int j = j0 + tx;
    if (j < OUT_DIM)
      tile[ty + r * 8][tx] = W[(size_t)(i0 + ty + r * 8) * OUT_DIM + j];
  }
  __syncthreads();
#pragma unroll
  for (int r = 0; r < 4; r++) {
    int j = j0 + ty + r * 8;
    if (j < OUT_DIM)
      Wt[(size_t)j * H_DIM + i0 + tx] = (__bf16)tile[tx][ty + r * 8];
  }
}

// ---- dense1: h = x @ W1 + b1 -> bf16 ----
__global__ __launch_bounds__(256) void dense1(const float* __restrict__ x,
                                              const float* __restrict__ W1,
                                              const float* __restrict__ b1,
                                              __bf16* __restrict__ h) {
  __shared__ float wsl[DIN * 256];
  __shared__ float xs[128 * DIN];
  int tid = threadIdx.x;
  int m0 = blockIdx.x * 128;
  int n0 = blockIdx.y * 256;
#pragma unroll
  for (int k = 0; k < DIN; k++) wsl[k * 256 + tid] = W1[k * H_DIM + n0 + tid];
  for (int idx = tid; idx < 128 * DIN; idx += 256) xs[idx] = x[(size_t)m0 * DIN + idx];
  __syncthreads();
  float wreg[DIN];
#pragma unroll
  for (int k = 0; k < DIN; k++) wreg[k] = wsl[k * 256 + tid];
  float bias = b1[n0 + tid];
  for (int m = 0; m < 128; m++) {
    float acc = bias;
#pragma unroll
    for (int k = 0; k < DIN; k++) acc += xs[m * DIN + k] * wreg[k];
    h[(size_t)(m0 + m) * H_DIM + n0 + tid] = (__bf16)acc;
  }
}

// ============ 256x256 / BK=32 / 4-deep pipelined gate GEMM (T3+T4) ============
// U = A(Mx1024) * Bt(3072x1024)^T; gates z|f|r; sigmoid(+bias) fused on f,r.
//
// LDS: 4 buffers x 32KB (A 16KB + B 16KB), strict rotation buf[t&3].
// Prefetch distance 3: at tile t stage tile t+3 into buf[(t+3)&3] — that
// buffer's reads (tile t-1) retired before the previous barrier (each wave's
// ds_reads are consumed by its MFMAs; barrier orders all waves). One raw
// s_barrier per K-tile, preceded by counted s_waitcnt vmcnt(8) (= stages for
// t+2,t+3 allowed in flight; tile t+1 guaranteed landed). Never vmcnt(0) in
// steady state (T4). Tail peeled: vmcnt(4), vmcnt(0), none.
//
// LDS layout (per A/B half): 128 "rowpairs" x 128B; rows 2r,2r+1 of the
// 256x32 bf16 K-slab packed per rowpair; 16B slot index XOR'd with (rp&7).
// Frag read (row = base+l15, kbyte = quad*16):
//   addr = rp*128 + (((row&1)<<6)|(quad<<4)) ^ ((rp&7)<<4),  rp = row>>1.
// Each 8-lane rp-group covers one full 128B row -> zero bank conflict.
// Staging is LINEAR in LDS (dest = tid*16, rule 21); the inverse permutation
// is applied to the per-lane GLOBAL source address:
//   sl = (tid&7) ^ ((tid>>3)&7);  row = p*128 + 2*(tid>>3) + (sl>>2);
//   kelem = (sl&3)*8.

__global__ __launch_bounds__(512, 2) void gemm_gate(const __bf16* __restrict__ A,
                                                    const __bf16* __restrict__ Bt,
                                                    __bf16* __restrict__ U,
                                                    const float* __restrict__ biasf,
                                                    const float* __restrict__ biasr) {
  __shared__ __align__(16) char lds[131072];
  int tid = threadIdx.x;
  int lane = tid & 63;
  int w = tid >> 6;          // wave 0..7
  int wm = w & 1, wn = w >> 1;

  // T1 bijective XCD-aware swizzle (gx is 32 or 64, both multiples of 8)
  int gx = gridDim.x;
  int lin = blockIdx.y * gx + blockIdx.x;
  int xcd = lin & 7;
  int kk = lin >> 3;
  int bx, by;
  if ((gx >> 3) == 8) { bx = xcd * 8 + (kk & 7); by = kk >> 3; }
  else                { bx = xcd * 4 + (kk & 3); by = kk >> 2; }
  int m0 = bx * 256, n0 = by * 256;

  // staging constants (per thread)
  int su = tid >> 3;                   // 0..63
  int ssl = (tid & 7) ^ (su & 7);      // slot_lin = stored slot ^ (rp&7)
  int srow = 2 * su + (ssl >> 2);      // global row within 128-row pass block
  int skel = (ssl & 3) * 8;            // k element offset (0,8,16,24)

  // frag-read constants
  int l15 = lane & 15;
  int quad = lane >> 4;
  int rpl = l15 >> 1;                  // rp low bits (= rp&7 for 16-aligned bases)
  int innerA = ((((l15 & 1) << 6) | (quad << 4)) ^ (rpl << 4));

  f32x4 acc[8][4];
#pragma unroll
  for (int i = 0; i < 8; ++i)
#pragma unroll
    for (int j = 0; j < 4; ++j) acc[i][j] = (f32x4)0.f;

  // 4 vm-ops per STAGE per thread (2 passes x {A,B})
#define STAGE(T_) do { int _t = (T_); int _bb = (_t & 3) * 32768;               \
    _Pragma("unroll") for (int _p = 0; _p < 2; ++_p) {                          \
      async16(A + (size_t)(m0 + _p * 128 + srow) * 1024 + _t * 32 + skel,       \
              (__bf16*)(lds + _bb + _p * 8192 + tid * 16));                     \
      async16(Bt + (size_t)(n0 + _p * 128 + srow) * 1024 + _t * 32 + skel,      \
              (__bf16*)(lds + _bb + 16384 + _p * 8192 + tid * 16));             \
    } } while (0)

#define COMPUTE(BUFB) do {                                                      \
    bf16x8 bF[4];                                                               \
    _Pragma("unroll") for (int fn = 0; fn < 4; ++fn)                            \
      bF[fn] = *(const bf16x8*)(lds + (BUFB) + 16384 +                          \
                 (wn * 32 + fn * 8 + rpl) * 128 + innerA);                      \
    __builtin_amdgcn_s_setprio(1);                                              \
    _Pragma("unroll") for (int fm = 0; fm < 8; ++fm) {                          \
      bf16x8 aF = *(const bf16x8*)(lds + (BUFB) +                               \
                 (wm * 64 + fm * 8 + rpl) * 128 + innerA);                      \
      _Pragma("unroll") for (int fn = 0; fn < 4; ++fn)                          \
        acc[fm][fn] = __builtin_amdgcn_mfma_f32_16x16x32_bf16(bF[fn], aF,       \
                          acc[fm][fn], 0, 0, 0);                                \
    }                                                                           \
    __builtin_amdgcn_s_setprio(0);                                              \
  } while (0)

  // prologue: stage tiles 0,1,2 (12 vm-ops); wait tile 0 (leave 8); barrier
  STAGE(0); STAGE(1); STAGE(2);
  asm volatile("s_waitcnt vmcnt(8)" ::: "memory");
  bar();

  // steady state: 32 K-tiles total; main loop t=0..28 stages t+3
  for (int t = 0; t < 29; ++t) {
    STAGE(t + 3);
    COMPUTE((t & 3) * 32768);
    asm volatile("s_waitcnt vmcnt(8)" ::: "memory");  // tile t+1 landed
    bar();
  }
  // t=29: no stage; allow tile-31 stages (4) outstanding
  COMPUTE((29 & 3) * 32768);
  asm volatile("s_waitcnt vmcnt(4)" ::: "memory");
  bar();
  // t=30: drain fully (tile 31 landed; nothing else in flight)
  COMPUTE((30 & 3) * 32768);
  asm volatile("s_waitcnt vmcnt(0)" ::: "memory");
  bar();
  // t=31: last tile; barrier before epilogue reuses LDS
  COMPUTE((31 & 3) * 32768);
  bar();
#undef STAGE
#undef COMPUTE

  // ---- epilogue (verified rounds 3-4, unchanged): swapped layout =>
  // n = wn*64+fn*16+quad*4+r, m = wm*128+fm*16+l15
  int gN[4];
  f32x4 bV[4];
#pragma unroll
  for (int fn = 0; fn < 4; ++fn) {
    int gc = n0 + wn * 64 + fn * 16 + quad * 4;
    int g = gc >> 10;  // 0=z,1=f,2=r (4-span never straddles: gc%4==0)
    gN[fn] = g;
    if (g == 1) bV[fn] = *(const f32x4*)&biasf[gc - 1024];
    else if (g == 2) bV[fn] = *(const f32x4*)&biasr[gc - 2048];
    else bV[fn] = (f32x4)0.f;
  }
  // stage whole 256x256 bf16 tile into the (now free) 128KB LDS
#pragma unroll
  for (int fm = 0; fm < 8; ++fm) {
    int m = wm * 128 + fm * 16 + l15;
    char* rowp = lds + m * 512;
    int msw = (m & 7) << 4;
#pragma unroll
    for (int fn = 0; fn < 4; ++fn) {
      int nq = wn * 64 + fn * 16 + quad * 4;
      f32x4 v = acc[fm][fn];
      if (gN[fn] != 0) {
#pragma unroll
        for (int j = 0; j < 4; ++j) v[j] = 1.f / (1.f + __expf(-(v[j] + bV[fn][j])));
      }
      bf16x4 o;
#pragma unroll
      for (int j = 0; j < 4; ++j) o[j] = (__bf16)v[j];
      *(bf16x4*)(rowp + ((nq * 2) ^ msw)) = o;
    }
  }
  bar();
  // copy out: 256 rows x 512B, 16B/lane, 512B-contiguous per 32-lane group
#pragma unroll
  for (int it = 0; it < 16; ++it) {
    int idx = it * 512 + tid;
    int row = idx >> 5;
    int ce = (idx & 31) * 8;
    bf16x8 val = *(const bf16x8*)(lds + row * 512 + ((ce * 2) ^ ((row & 7) << 4)));
    *(bf16x8*)&U[(size_t)(m0 + row) * H3 + n0 + ce] = val;
  }
}

// ---- output GEMM (m97 128x128 structure, known-good): out = h@W3t^T + b3 ----
__global__ __launch_bounds__(256) void gemm_out(const __bf16* __restrict__ A,
                                                const __bf16* __restrict__ Bt,
                                                float* __restrict__ C,
                                                const float* __restrict__ bias0) {
  constexpr int K = 1024;
  __shared__ __align__(16) __bf16 sA[128 * 32];
  __shared__ __align__(16) __bf16 sB[128 * 32];
  int tid = threadIdx.x;
  int lane = tid & 63;
  int wave = tid >> 6;
  int wm = wave & 1, wn = wave >> 1;
  int m0 = blockIdx.x * 128;
  int n0 = blockIdx.y * 128;

  f32x4 acc[4][4];
#pragma unroll
  for (int i = 0; i < 4; i++)
#pragma unroll
    for (int j = 0; j < 4; j++) acc[i][j] = (f32x4)0.f;

  int lrow = lane >> 2;
  int lcol8 = (lane & 3) * 8;
  int q8 = (lane >> 4) * 8;
  int l15 = lane & 15;

  for (int k0 = 0; k0 < K; k0 += 32) {
    __syncthreads();
#pragma unroll
    for (int i = 0; i < 2; i++) {
      int j = wave * 2 + i;
      int arow = m0 + j * 16 + lrow;
      async16(A + (size_t)arow * K + k0 + lcol8, &sA[j * 512]);
      int brow = n0 + j * 16 + lrow;
      brow = brow < OUT_DIM - 1 ? brow : OUT_DIM - 1;
      async16(Bt + (size_t)brow * K + k0 + lcol8, &sB[j * 512]);
    }
    __syncthreads();
    bf16x8 aF[4], bF[4];
#pragma unroll
    for (int i = 0; i < 4; i++) {
      aF[i] = *(const bf16x8*)&sA[(wm * 64 + i * 16 + l15) * 32 + q8];
      bF[i] = *(const bf16x8*)&sB[(wn * 64 + i * 16 + l15) * 32 + q8];
    }
#pragma unroll
    for (int mi = 0; mi < 4; mi++)
#pragma unroll
      for (int ni = 0; ni < 4; ni++)
        acc[mi][ni] = __builtin_amdgcn_mfma_f32_16x16x32_bf16(aF[mi], bF[ni], acc[mi][ni], 0, 0, 0);
  }

  int quad = lane >> 4;
#pragma unroll
  for (int mi = 0; mi < 4; mi++) {
    int rowBase = m0 + wm * 64 + mi * 16 + quad * 4;
#pragma unroll
    for (int ni = 0; ni < 4; ni++) {
      int col = n0 + wn * 64 + ni * 16 + l15;
      if (col < OUT_DIM) {
        float badd = bias0[col];
#pragma unroll
        for (int r = 0; r < 4; r++)
          C[(size_t)(rowBase + r) * OUT_DIM + col] = acc[mi][ni][r] + badd;
      }
    }
  }
}

// ---- SRU scan over a T-chunk; h updated in place; c carried fp32 in ws ----
__global__ __launch_bounds__(256) void sru_scan(const __bf16* __restrict__ U,
                                                __bf16* __restrict__ h,
                                                float* __restrict__ cst,
                                                float* __restrict__ cfin,
                                                int tc, int first, int last) {
  int id = blockIdx.x * 256 + threadIdx.x;
  int n2 = id * 2;
  int b = n2 >> 10;
  int hh = n2 & 1023;
  float c0, c1;
  if (first) { c0 = 0.f; c1 = 0.f; }
  else { c0 = cst[n2]; c1 = cst[n2 + 1]; }
  size_t ub = (size_t)b * H3 + hh;
  size_t xb = (size_t)b * H_DIM + hh;
  const size_t strideU = (size_t)B_DIM * H3;
  const size_t strideH = (size_t)B_DIM * H_DIM;
  for (int t = 0; t < tc; t++) {
    bf16x2 z2 = *(const bf16x2*)&U[ub];
    bf16x2 f2 = *(const bf16x2*)&U[ub + 1024];
    bf16x2 r2 = *(const bf16x2*)&U[ub + 2048];
    bf16x2 x2 = *(const bf16x2*)&h[xb];
    float f0 = (float)f2[0], f1 = (float)f2[1];
    float r0 = (float)r2[0], r1 = (float)r2[1];
    c0 = f0 * c0 + (1.f - f0) * (float)z2[0];
    c1 = f1 * c1 + (1.f - f1) * (float)z2[1];
    float h0 = r0 * c0 + (1.f - r0) * (float)x2[0];
    float h1 = r1 * c1 + (1.f - r1) * (float)x2[1];
    bf16x2 o;
    o[0] = (__bf16)h0;
    o[1] = (__bf16)h1;
    *(bf16x2*)&h[xb] = o;
    ub += strideU;
    xb += strideH;
  }
  cst[n2] = c0;
  cst[n2 + 1] = c1;
  if (last) {
    cfin[n2] = c0;
    cfin[n2 + 1] = c1;
  }
}

extern "C" void kernel_launch(void* const* d_in, const int* in_sizes, int n_in,
                              void* d_out, int out_size, void* d_ws, size_t ws_size,
                              hipStream_t stream) {
  const float* x = (const float*)d_in[0];
  const float* W1 = (const float*)d_in[2];
  const float* b1 = (const float*)d_in[3];
  const float* Wsru = (const float*)d_in[4];
  const float* bf_s = (const float*)d_in[5];
  const float* br_s = (const float*)d_in[6];
  const float* W3 = (const float*)d_in[7];
  const float* b3 = (const float*)d_in[8];
  float* out = (float*)d_out;

  // chunk size: prefer 128 (grid 768 = 3 full CU-rounds) if workspace allows
  const size_t kFixed = 67108864ull + 18874368ull + 2242560ull + 524288ull;
  int tch = (ws_size >= kFixed + (size_t)128 * B_DIM * H3 * 2) ? 128 : 64;
  int mch = tch * B_DIM;
  int nch = T_DIM / tch;

  // workspace layout
  char* wsb = (char*)d_ws;
  __bf16* h = (__bf16*)(wsb);                                  // 67,108,864
  __bf16* U = (__bf16*)(wsb + 67108864);                       // mch*3072*2
  char* wAfter = wsb + 67108864 + (size_t)mch * H3 * 2;
  __bf16* Wt = (__bf16*)(wAfter);                              // 18,874,368
  __bf16* W3t = (__bf16*)(wAfter + 18874368);                  //  2,242,560
  float* cst = (float*)(wAfter + 18874368 + 2242560);          //    524,288

  transpose_sru<<<dim3(H3 / 32, H_DIM / 32, L_DIM), dim3(32, 8), 0, stream>>>(Wsru, Wt);
  transpose_w3<<<dim3((OUT_DIM + 31) / 32, H_DIM / 32), dim3(32, 8), 0, stream>>>(W3, W3t);
  dense1<<<dim3(M_DIM / 128, H_DIM / 256), 256, 0, stream>>>(x, W1, b1, h);

  for (int l = 0; l < L_DIM; l++) {
    const __bf16* Wtl = Wt + (size_t)l * H_DIM * H3;
    const float* bfl = bf_s + l * H_DIM;
    const float* brl = br_s + l * H_DIM;
    float* cfin = out + OUT_ELEMS + (size_t)l * B_DIM * H_DIM;
    for (int ch = 0; ch < nch; ch++) {
      __bf16* hA = h + (size_t)ch * mch * H_DIM;
      gemm_gate<<<dim3(mch / 256, H3 / 256), 512, 0, stream>>>(hA, Wtl, U, bfl, brl);
      sru_scan<<<dim3(B_DIM * H_DIM / 512), 256, 0, stream>>>(
          U, hA, cst, cfin, tch, ch == 0 ? 1 : 0, ch == (nch - 1) ? 1 : 0);
    }
  }

  gemm_out<<<dim3(M_DIM / 128, (OUT_DIM + 127) / 128), 256, 0, stream>>>(h, W3t, out, b3);
}

// Round 6
// 1239.221 us; speedup vs baseline: 1.0738x; 1.0738x over previous
//
#include <hip/hip_runtime.h>
#include <hip/hip_bf16.h>

// Problem: T=256, B=128, DIN=20, H=1024, OUT=1095, L=3
//   h = x @ W1 + b1                       (T*B,20)x(20,1024)
//   3x SRU: U = h @ W_sru[l]  (T*B,1024)x(1024,3072); gates z|f|r
//           scan over T: c = f*c + (1-f)*z ; h = r*c + (1-r)*h_in
//   out = h @ W3 + b3                     (T*B,1024)x(1024,1095)
// fp32 in/out; bf16 MFMA internally, fp32 accumulate, c carried fp32.

#define T_DIM 256
#define B_DIM 128
#define DIN 20
#define H_DIM 1024
#define OUT_DIM 1095
#define L_DIM 3
#define M_DIM (T_DIM * B_DIM)        // 32768
#define H3 (3 * H_DIM)               // 3072
#define OUT_ELEMS ((size_t)M_DIM * OUT_DIM)   // 35,880,960

typedef __bf16 bf16x8 __attribute__((ext_vector_type(8)));
typedef __bf16 bf16x4 __attribute__((ext_vector_type(4)));
typedef __bf16 bf16x2 __attribute__((ext_vector_type(2)));
typedef float f32x4 __attribute__((ext_vector_type(4)));

__device__ __forceinline__ void async16(const __bf16* g, __bf16* l) {
  __builtin_amdgcn_global_load_lds(
      (const __attribute__((address_space(1))) void*)g,
      (__attribute__((address_space(3))) void*)l, 16, 0, 0);
}

// ---- transpose + cast W_sru (L,H,3H) fp32 -> (L,3H,H) bf16 ----
__global__ void transpose_sru(const float* __restrict__ W, __bf16* __restrict__ Wt) {
  __shared__ float tile[32][33];
  int l = blockIdx.z;
  int j0 = blockIdx.x * 32;
  int i0 = blockIdx.y * 32;
  int tx = threadIdx.x, ty = threadIdx.y;  // 32x8
  const float* Wl = W + (size_t)l * H_DIM * H3;
  __bf16* Wtl = Wt + (size_t)l * H_DIM * H3;
#pragma unroll
  for (int r = 0; r < 4; r++)
    tile[ty + r * 8][tx] = Wl[(size_t)(i0 + ty + r * 8) * H3 + j0 + tx];
  __syncthreads();
#pragma unroll
  for (int r = 0; r < 4; r++)
    Wtl[(size_t)(j0 + ty + r * 8) * H_DIM + i0 + tx] = (__bf16)tile[tx][ty + r * 8];
}

// ---- transpose + cast W3 (H,OUT) fp32 -> (OUT,H) bf16 ----
__global__ void transpose_w3(const float* __restrict__ W, __bf16* __restrict__ Wt) {
  __shared__ float tile[32][33];
  int j0 = blockIdx.x * 32;
  int i0 = blockIdx.y * 32;
  int tx = threadIdx.x, ty = threadIdx.y;
#pragma unroll
  for (int r = 0; r < 4; r++) {
    int j = j0 + tx;
    if (j < OUT_DIM)
      tile[ty + r * 8][tx] = W[(size_t)(i0 + ty + r * 8) * OUT_DIM + j];
  }
  __syncthreads();
#pragma unroll
  for (int r = 0; r < 4; r++) {
    int j = j0 + ty + r * 8;
    if (j < OUT_DIM)
      Wt[(size_t)j * H_DIM + i0 + tx] = (__bf16)tile[tx][ty + r * 8];
  }
}

// ---- dense1: h = x @ W1 + b1 -> bf16 ----
__global__ __launch_bounds__(256) void dense1(const float* __restrict__ x,
                                              const float* __restrict__ W1,
                                              const float* __restrict__ b1,
                                              __bf16* __restrict__ h) {
  __shared__ float wsl[DIN * 256];
  __shared__ float xs[128 * DIN];
  int tid = threadIdx.x;
  int m0 = blockIdx.x * 128;
  int n0 = blockIdx.y * 256;
#pragma unroll
  for (int k = 0; k < DIN; k++) wsl[k * 256 + tid] = W1[k * H_DIM + n0 + tid];
  for (int idx = tid; idx < 128 * DIN; idx += 256) xs[idx] = x[(size_t)m0 * DIN + idx];
  __syncthreads();
  float wreg[DIN];
#pragma unroll
  for (int k = 0; k < DIN; k++) wreg[k] = wsl[k * 256 + tid];
  float bias = b1[n0 + tid];
  for (int m = 0; m < 128; m++) {
    float acc = bias;
#pragma unroll
    for (int k = 0; k < DIN; k++) acc += xs[m * DIN + k] * wreg[k];
    h[(size_t)(m0 + m) * H_DIM + n0 + tid] = (__bf16)acc;
  }
}

// ================= 256x256 / BK=64 / 8-wave 2-phase GEMM (verified R4) =======
// C = A(Mx1024) * Bt(Nx1024)^T.
// EPI 1 (SRU gates): swapped-operand MFMA (acc row = N, col = M), sigmoid(+bias)
//        fused on f,r; packed bf16x4 -> LDS-staged -> coalesced bf16 stores.
// EPI 0 (output): normal operand order, scalar fp32 stores (64B row segments;
//        C rows are only 4B-aligned so vector stores are illegal), bias add,
//        col<Ntotal predicate; B staging rows clamped to Ntotal-1 (clamped
//        rows feed only predicated-off columns).
// Sync: per K-tile { STAGE next tile (other buf); ds_read + 64 MFMA (cur buf);
// __syncthreads() (implicit vmcnt(0) drain IS the sync) }.
// T2 XOR-swizzle (rule #21): linear LDS dest, pre-swizzled global source,
// swizzled read addr. T1 bijective XCD swizzle. T5 setprio around MFMA.

template <int MH, int EPI>
__device__ __forceinline__ void mfma16(f32x4 (&acc)[8][4], const bf16x8 (&aF)[4],
                                       const bf16x8 (&bF)[4]) {
  __builtin_amdgcn_s_setprio(1);
#pragma unroll
  for (int i = 0; i < 4; ++i)
#pragma unroll
    for (int fn = 0; fn < 4; ++fn) {
      if (EPI == 1)
        acc[MH * 4 + i][fn] =
            __builtin_amdgcn_mfma_f32_16x16x32_bf16(bF[fn], aF[i], acc[MH * 4 + i][fn], 0, 0, 0);
      else
        acc[MH * 4 + i][fn] =
            __builtin_amdgcn_mfma_f32_16x16x32_bf16(aF[i], bF[fn], acc[MH * 4 + i][fn], 0, 0, 0);
    }
  __builtin_amdgcn_s_setprio(0);
}

template <int EPI>
__global__ __launch_bounds__(512, 2) void gemm256(const __bf16* __restrict__ A,
                                                  const __bf16* __restrict__ Bt,
                                                  void* __restrict__ Cv,
                                                  const float* __restrict__ bias0,
                                                  const float* __restrict__ bias1,
                                                  int Ntotal, int ldc) {
  __shared__ __align__(16) char lds[131072];
  int tid = threadIdx.x;
  int lane = tid & 63;
  int w = tid >> 6;          // wave 0..7
  int wm = w & 1, wn = w >> 1;

  // T1 bijective XCD-aware swizzle; gx in {32,64,128}, grid % 8 == 0
  int gx = gridDim.x;
  int lin = blockIdx.y * gx + blockIdx.x;
  int xcd = lin & 7;
  int kk = lin >> 3;
  int bpx = gx >> 3;                     // power of 2 (4/8/16)
  int sh = __builtin_ctz(bpx);
  int bx = xcd * bpx + (kk & (bpx - 1));
  int by = kk >> sh;
  int m0 = bx * 256, n0 = by * 256;

  int r8row = w * 8 + (lane >> 3);          // row staged (within 64-row unit); row&7 = lane>>3
  int cse = (((lane & 7) ^ (lane >> 3)) * 8); // pre-swizzled SOURCE element col
  int l15 = lane & 15;
  int quad = lane >> 4;
  int asw = (lane & 7) << 4;                // read-side swizzle (frag row&7 = lane&7)

  f32x4 acc[8][4];
#pragma unroll
  for (int i = 0; i < 8; ++i)
#pragma unroll
    for (int j = 0; j < 4; ++j) acc[i][j] = (f32x4)0.f;
  bf16x8 aF[4], bF[4];

  // LDS per buffer (64KB): A = 256 rows x 128B at +0, B at +32768.
  // Wave w stages rows w*8..w*8+7 of each 64-row unit; dest linear (HW rule).
#define STAGE_TILE(T_) do { int _t = (T_); int _b = (_t & 1) * 65536;            \
    _Pragma("unroll") for (int _u = 0; _u < 4; ++_u)                             \
      async16(A + (size_t)(m0 + _u * 64 + r8row) * 1024 + _t * 64 + cse,         \
              (__bf16*)(lds + _b + _u * 8192 + w * 1024));                       \
    _Pragma("unroll") for (int _u = 0; _u < 4; ++_u) {                           \
      int _br = n0 + _u * 64 + r8row;                                            \
      if (EPI == 0 && _br > Ntotal - 1) _br = Ntotal - 1;                        \
      async16(Bt + (size_t)_br * 1024 + _t * 64 + cse,                           \
              (__bf16*)(lds + _b + 32768 + _u * 8192 + w * 1024));               \
    } } while (0)

#define LOAD_A(MH_, KS_) do {                                                    \
    _Pragma("unroll") for (int i = 0; i < 4; ++i)                                \
      aF[i] = *(const bf16x8*)(lds + bufc +                                      \
                (wm * 128 + (MH_) * 64 + i * 16 + l15) * 128 +                   \
                ((quad * 16 + (KS_) * 64) ^ asw)); } while (0)

#define LOAD_B(KS_) do {                                                         \
    _Pragma("unroll") for (int i = 0; i < 4; ++i)                                \
      bF[i] = *(const bf16x8*)(lds + bufc + 32768 +                              \
                (wn * 64 + i * 16 + l15) * 128 +                                 \
                ((quad * 16 + (KS_) * 64) ^ asw)); } while (0)

  // prologue: stage tile 0; __syncthreads drains it
  STAGE_TILE(0);
  __syncthreads();

#pragma unroll 2
  for (int t = 0; t < 16; ++t) {
    int bufc = (t & 1) * 65536;
    if (t < 15) STAGE_TILE(t + 1);   // issue BEFORE compute; lands by the barrier
    LOAD_B(0);
    LOAD_A(0, 0); mfma16<0, EPI>(acc, aF, bF);
    LOAD_A(1, 0); mfma16<1, EPI>(acc, aF, bF);
    LOAD_B(1);
    LOAD_A(0, 1); mfma16<0, EPI>(acc, aF, bF);
    LOAD_A(1, 1); mfma16<1, EPI>(acc, aF, bF);
    __syncthreads();                 // implicit vmcnt(0): next tile fully landed
  }
#undef STAGE_TILE
#undef LOAD_A
#undef LOAD_B

  if (EPI == 1) {
    // ---- gate epilogue (verified R3/R4): swapped layout =>
    // n = wn*64+fn*16+quad*4+r, m = wm*128+fm*16+l15
    __bf16* U = (__bf16*)Cv;
    int gN[4];
    f32x4 bV[4];
#pragma unroll
    for (int fn = 0; fn < 4; ++fn) {
      int gc = n0 + wn * 64 + fn * 16 + quad * 4;
      int g = gc >> 10;  // 0=z,1=f,2=r (4-span never straddles: gc%4==0)
      gN[fn] = g;
      if (g == 1) bV[fn] = *(const f32x4*)&bias0[gc - 1024];
      else if (g == 2) bV[fn] = *(const f32x4*)&bias1[gc - 2048];
      else bV[fn] = (f32x4)0.f;
    }
    // stage whole 256x256 bf16 tile into the (now free) 128KB LDS
#pragma unroll
    for (int fm = 0; fm < 8; ++fm) {
      int m = wm * 128 + fm * 16 + l15;
      char* rowp = lds + m * 512;
      int msw = (m & 7) << 4;
#pragma unroll
      for (int fn = 0; fn < 4; ++fn) {
        int nq = wn * 64 + fn * 16 + quad * 4;
        f32x4 v = acc[fm][fn];
        if (gN[fn] != 0) {
#pragma unroll
          for (int j = 0; j < 4; ++j) v[j] = 1.f / (1.f + __expf(-(v[j] + bV[fn][j])));
        }
        bf16x4 o;
#pragma unroll
        for (int j = 0; j < 4; ++j) o[j] = (__bf16)v[j];
        *(bf16x4*)(rowp + ((nq * 2) ^ msw)) = o;
      }
    }
    __syncthreads();
    // copy out: 256 rows x 512B, 16B/lane, 512B-contiguous per 32-lane group
#pragma unroll
    for (int it = 0; it < 16; ++it) {
      int idx = it * 512 + tid;
      int row = idx >> 5;
      int ce = (idx & 31) * 8;
      bf16x8 val = *(const bf16x8*)(lds + row * 512 + ((ce * 2) ^ ((row & 7) << 4)));
      *(bf16x8*)&U[(size_t)(m0 + row) * ldc + n0 + ce] = val;
    }
  } else {
    // ---- output epilogue: normal layout => m = wm*128+fm*16+quad*4+r,
    // n = wn*64+fn*16+l15. Scalar fp32 stores: 16 l15-lanes = 64B segments.
    float* C = (float*)Cv;
#pragma unroll
    for (int fm = 0; fm < 8; ++fm) {
      int rowBase = m0 + wm * 128 + fm * 16 + quad * 4;
#pragma unroll
      for (int fn = 0; fn < 4; ++fn) {
        int col = n0 + wn * 64 + fn * 16 + l15;
        if (col < Ntotal) {
          float badd = bias0[col];
#pragma unroll
          for (int r = 0; r < 4; ++r)
            C[(size_t)(rowBase + r) * ldc + col] = acc[fm][fn][r] + badd;
        }
      }
    }
  }
}

// ---- SRU scan over a T-chunk; h updated in place; c carried fp32 in ws ----
// Explicit next-iteration prefetch (loads for t+1 issued before t's compute)
// to deepen the in-flight load queue at 4 waves/CU; last step peeled.
__global__ __launch_bounds__(256) void sru_scan(const __bf16* __restrict__ U,
                                                __bf16* __restrict__ h,
                                                float* __restrict__ cst,
                                                float* __restrict__ cfin,
                                                int tc, int first, int last) {
  int id = blockIdx.x * 256 + threadIdx.x;
  int n2 = id * 2;
  int b = n2 >> 10;
  int hh = n2 & 1023;
  float c0, c1;
  if (first) { c0 = 0.f; c1 = 0.f; }
  else { c0 = cst[n2]; c1 = cst[n2 + 1]; }
  size_t ub = (size_t)b * H3 + hh;
  size_t xb = (size_t)b * H_DIM + hh;
  const size_t strideU = (size_t)B_DIM * H3;
  const size_t strideH = (size_t)B_DIM * H_DIM;

  bf16x2 z2 = *(const bf16x2*)&U[ub];
  bf16x2 f2 = *(const bf16x2*)&U[ub + 1024];
  bf16x2 r2 = *(const bf16x2*)&U[ub + 2048];
  bf16x2 x2 = *(const bf16x2*)&h[xb];

  for (int t = 0; t < tc - 1; t++) {
    size_t ubn = ub + strideU, xbn = xb + strideH;
    bf16x2 z2n = *(const bf16x2*)&U[ubn];
    bf16x2 f2n = *(const bf16x2*)&U[ubn + 1024];
    bf16x2 r2n = *(const bf16x2*)&U[ubn + 2048];
    bf16x2 x2n = *(const bf16x2*)&h[xbn];

    float f0 = (float)f2[0], f1 = (float)f2[1];
    float r0 = (float)r2[0], r1 = (float)r2[1];
    c0 = f0 * c0 + (1.f - f0) * (float)z2[0];
    c1 = f1 * c1 + (1.f - f1) * (float)z2[1];
    float h0 = r0 * c0 + (1.f - r0) * (float)x2[0];
    float h1 = r1 * c1 + (1.f - r1) * (float)x2[1];
    bf16x2 o;
    o[0] = (__bf16)h0;
    o[1] = (__bf16)h1;
    *(bf16x2*)&h[xb] = o;

    z2 = z2n; f2 = f2n; r2 = r2n; x2 = x2n;
    ub = ubn; xb = xbn;
  }
  // last step
  {
    float f0 = (float)f2[0], f1 = (float)f2[1];
    float r0 = (float)r2[0], r1 = (float)r2[1];
    c0 = f0 * c0 + (1.f - f0) * (float)z2[0];
    c1 = f1 * c1 + (1.f - f1) * (float)z2[1];
    float h0 = r0 * c0 + (1.f - r0) * (float)x2[0];
    float h1 = r1 * c1 + (1.f - r1) * (float)x2[1];
    bf16x2 o;
    o[0] = (__bf16)h0;
    o[1] = (__bf16)h1;
    *(bf16x2*)&h[xb] = o;
  }
  cst[n2] = c0;
  cst[n2 + 1] = c1;
  if (last) {
    cfin[n2] = c0;
    cfin[n2 + 1] = c1;
  }
}

extern "C" void kernel_launch(void* const* d_in, const int* in_sizes, int n_in,
                              void* d_out, int out_size, void* d_ws, size_t ws_size,
                              hipStream_t stream) {
  const float* x = (const float*)d_in[0];
  const float* W1 = (const float*)d_in[2];
  const float* b1 = (const float*)d_in[3];
  const float* Wsru = (const float*)d_in[4];
  const float* bf_s = (const float*)d_in[5];
  const float* br_s = (const float*)d_in[6];
  const float* W3 = (const float*)d_in[7];
  const float* b3 = (const float*)d_in[8];
  float* out = (float*)d_out;

  // chunk size: prefer 128 (grid 768 = 3 full CU-rounds) if workspace allows
  const size_t kFixed = 67108864ull + 18874368ull + 2242560ull + 524288ull;
  int tch = (ws_size >= kFixed + (size_t)128 * B_DIM * H3 * 2) ? 128 : 64;
  int mch = tch * B_DIM;
  int nch = T_DIM / tch;

  // workspace layout
  char* wsb = (char*)d_ws;
  __bf16* h = (__bf16*)(wsb);                                  // 67,108,864
  __bf16* U = (__bf16*)(wsb + 67108864);                       // mch*3072*2
  char* wAfter = wsb + 67108864 + (size_t)mch * H3 * 2;
  __bf16* Wt = (__bf16*)(wAfter);                              // 18,874,368
  __bf16* W3t = (__bf16*)(wAfter + 18874368);                  //  2,242,560
  float* cst = (float*)(wAfter + 18874368 + 2242560);          //    524,288

  transpose_sru<<<dim3(H3 / 32, H_DIM / 32, L_DIM), dim3(32, 8), 0, stream>>>(Wsru, Wt);
  transpose_w3<<<dim3((OUT_DIM + 31) / 32, H_DIM / 32), dim3(32, 8), 0, stream>>>(W3, W3t);
  dense1<<<dim3(M_DIM / 128, H_DIM / 256), 256, 0, stream>>>(x, W1, b1, h);

  for (int l = 0; l < L_DIM; l++) {
    const __bf16* Wtl = Wt + (size_t)l * H_DIM * H3;
    const float* bfl = bf_s + l * H_DIM;
    const float* brl = br_s + l * H_DIM;
    float* cfin = out + OUT_ELEMS + (size_t)l * B_DIM * H_DIM;
    for (int ch = 0; ch < nch; ch++) {
      __bf16* hA = h + (size_t)ch * mch * H_DIM;
      gemm256<1><<<dim3(mch / 256, H3 / 256), 512, 0, stream>>>(hA, Wtl, U, bfl, brl, H3, H3);
      sru_scan<<<dim3(B_DIM * H_DIM / 512), 256, 0, stream>>>(
          U, hA, cst, cfin, tch, ch == 0 ? 1 : 0, ch == (nch - 1) ? 1 : 0);
    }
  }

  // output GEMM on the same verified 256^2 structure: grid 128 x 5 = 640 (%8==0)
  gemm256<0><<<dim3(M_DIM / 256, (OUT_DIM + 255) / 256), 512, 0, stream>>>(
      h, W3t, out, b3, nullptr, OUT_DIM, OUT_DIM);
}